// Round 7
// baseline (123.782 us; speedup 1.0000x reference)
//
#include <hip/hip_runtime.h>

typedef unsigned short u16;
typedef unsigned int u32;
using frag8 = __attribute__((ext_vector_type(8))) short;  // 8 bf16 (4 VGPRs)
using f32x4 = __attribute__((ext_vector_type(4))) float;
using u32x4 = __attribute__((ext_vector_type(4))) u32;

#define MFMA(a, b, c) __builtin_amdgcn_mfma_f32_16x16x32_bf16(a, b, c, 0, 0, 0)

// fp32 -> bf16, round-to-nearest-even (finite inputs only)
__device__ __forceinline__ u16 f2bf(float f) {
  u32 x = __float_as_uint(f);
  x += 0x7fffu + ((x >> 16) & 1u);
  return (u16)(x >> 16);
}

// ---------------------------------------------------------------------------
// Pre-pass: qkv (4,1536,2048) fp32 ->
//   Qt[b][t][c] bf16 (scaled), Kt[b][s][c] bf16 (scaled),
//   Vn[b][c][s'] bf16 with s sigma-PERMUTED within each 64-s tile:
//     stored position p (h=p>>5, w=(p>>3)&3, e=p&7) holds original
//     s = 32h + 16*(e>>2) + 4w + (e&3).
// The permutation maps each 32-s half onto itself, so 32-s tiles stay valid.
// Makes QK^T's D-fragment directly usable as PV's B-fragment (k-permutation
// cancels between P and V) -> P stays in registers in the flash kernel.
// ---------------------------------------------------------------------------
__global__ __launch_bounds__(256) void qkv_prepass_kernel(
    const float* __restrict__ qkv, u16* __restrict__ Qt, u16* __restrict__ Kt,
    u16* __restrict__ Vn) {
  __shared__ float tile[64 * 65];
  const int id = blockIdx.x;
  const int tid = threadIdx.x;

  if (id < 2048) {
    const bool isK = id >= 1024;
    const int lid = isK ? (id - 1024) : id;
    const int b = lid >> 5;
    const int t0 = (lid & 31) * 64;
    const int bs = b >> 3, h = b & 7;
    const float* src =
        qkv + ((size_t)(bs * 1536 + h * 192 + (isK ? 64 : 0))) * 2048 + t0;
    u16* dst = (isK ? Kt : Qt) + ((size_t)b * 2048 + t0) * 64;
    const float scale = 0.42466090014400953f;  // 64^-0.25 * sqrt(log2 e)

    const int t4 = (tid & 15) * 4;
    const int c = tid >> 4;
#pragma unroll
    for (int i = 0; i < 4; ++i) {
      int cc = c + 16 * i;
      float4 f = *reinterpret_cast<const float4*>(src + (size_t)cc * 2048 + t4);
      tile[cc * 65 + t4 + 0] = f.x * scale;
      tile[cc * 65 + t4 + 1] = f.y * scale;
      tile[cc * 65 + t4 + 2] = f.z * scale;
      tile[cc * 65 + t4 + 3] = f.w * scale;
    }
    __syncthreads();
    const int c0 = (tid & 7) * 8;
#pragma unroll
    for (int p = 0; p < 2; ++p) {
      int tr = (tid >> 3) + 32 * p;
      u32 pk[4];
#pragma unroll
      for (int uu = 0; uu < 4; ++uu) {
        u16 lo = f2bf(tile[(c0 + 2 * uu) * 65 + tr]);
        u16 hi = f2bf(tile[(c0 + 2 * uu + 1) * 65 + tr]);
        pk[uu] = (u32)lo | ((u32)hi << 16);
      }
      *reinterpret_cast<uint4*>(dst + (size_t)tr * 64 + c0) =
          make_uint4(pk[0], pk[1], pk[2], pk[3]);
    }
  } else {
    const size_t base = (size_t)(id - 2048) * 4096;
#pragma unroll
    for (int it = 0; it < 2; ++it) {
      size_t vi = base + (size_t)it * 2048 + (size_t)tid * 8;
      int b = (int)(vi >> 17);
      int r = (int)(vi & 131071);
      int bs = b >> 3, h = b & 7;
      int col = r & 2047;      // stored position within the c-row
      int rowoff = r - col;    // c * 2048
      int m = (col >> 3) & 7;  // 8-run index within the 64-s tile
      // source column of stored e=0..3 run: tilebase + 32h + 4w
      int c0 = (col & ~63) | ((m >> 2) << 5) | ((m & 3) << 2);
      const float* sp =
          qkv + ((size_t)(bs * 1536 + h * 192 + 128)) * 2048 + rowoff;
      float4 f0 = *reinterpret_cast<const float4*>(sp + c0);       // e=0..3
      float4 f1 = *reinterpret_cast<const float4*>(sp + c0 + 16);  // e=4..7
      uint4 pk;
      pk.x = (u32)f2bf(f0.x) | ((u32)f2bf(f0.y) << 16);
      pk.y = (u32)f2bf(f0.z) | ((u32)f2bf(f0.w) << 16);
      pk.z = (u32)f2bf(f1.x) | ((u32)f2bf(f1.y) << 16);
      pk.w = (u32)f2bf(f1.z) | ((u32)f2bf(f1.w) << 16);
      *reinterpret_cast<uint4*>(Vn + vi) = pk;
    }
  }
}

// ---------------------------------------------------------------------------
// Flash attention R7: counted-vmcnt pipeline (T3/T4), 3-buffer K/V.
// block = 512 threads = 8 waves = 4 t-groups (32 t) x 2 s-halves (1024 s).
// R6's __syncthreads per step lowered to a full vmcnt(0) drain -> every step
// serialized on staging latency for all 8 waves. R7: raw s_barrier with
// s_waitcnt vmcnt(2) at the step head -- tile n+1's loads stay in flight
// ACROSS the barrier (2 steps of latency cover), never draining mid-loop.
// Step n consumes buf[n%3], stages tile n+2 into buf[(n+2)%3] (issued after
// the step-n head barrier, which orders it after all step n-1 reads).
// Q fragments are loaded directly global->VGPR (the staging XOR cancels:
// lane reads Qg + row*64 + q*8, coalesced) -- no Q LDS, no prologue barrier.
// LDS: 3 bufs x 8192 u16 (16 KiB) = 48 KiB; per buf: K sh0/sh1 [0,4096),
// V sh0/sh1 [4096,8192). Epilogue float exchange reuses [0,36 KiB).
// 2 blocks/CU x 48 KiB = 96 <= 160 KiB; __launch_bounds__(512,4) -> <=128
// VGPR for 4 waves/SIMD.
// ---------------------------------------------------------------------------
#define STAGE(dstOff, srcPtr)                                                  \
  __builtin_amdgcn_global_load_lds(                                            \
      (const __attribute__((address_space(1))) void*)(srcPtr),                 \
      (__attribute__((address_space(3))) void*)(ldsbase + (dstOff) + tid * 8), \
      16, 0, 0)

// stage K tile N (both s-halves) + V tile N into buf B (2 loads/thread)
#define STG_STEP(N, B)                  \
  STAGE((B), kS + (size_t)(N) * 2048); \
  STAGE((B) + 4096, vS + (N) * 32);

// step head: wait for this step's tile (leave newer loads in flight), then
// barrier; sched_barrier stops ds_reads/MFMA hoisting above it (rule 18)
#define WAITB(N)                                        \
  asm volatile("s_waitcnt vmcnt(" #N ")" ::: "memory"); \
  __builtin_amdgcn_s_barrier();                         \
  __builtin_amdgcn_sched_barrier(0);

// compute one 32-s tile from buf CUR; issue STG for tile n+2 (no barrier --
// the next step's WAITB provides it)
#define BODY(CUR, STG)                                                      \
  {                                                                         \
    frag8 kf0[2], kf1[2];                                                   \
    _Pragma("unroll") for (int i = 0; i < 2; ++i) {                         \
      kf0[i] = *(const frag8*)(ldsbase + (CUR) + kAo + i * 1024);           \
      kf1[i] = *(const frag8*)(ldsbase + (CUR) + kBo + i * 1024);           \
    }                                                                       \
    STG                                                                     \
    f32x4 S[2][2];                                                          \
    __builtin_amdgcn_s_setprio(1);                                          \
    _Pragma("unroll") for (int j = 0; j < 2; ++j) {                         \
      _Pragma("unroll") for (int i = 0; i < 2; ++i) {                       \
        f32x4 z = {0.f, 0.f, 0.f, 0.f};                                     \
        z = MFMA(kf0[i], aQ0[j], z);                                        \
        z = MFMA(kf1[i], aQ1[j], z);                                        \
        S[i][j] = z;                                                        \
      }                                                                     \
    }                                                                       \
    __builtin_amdgcn_s_setprio(0);                                          \
    frag8 vf[4];                                                            \
    _Pragma("unroll") for (int i = 0; i < 4; ++i)                           \
      vf[i] = *(const frag8*)(ldsbase + (CUR) + vAo + i * 512);             \
    _Pragma("unroll") for (int j = 0; j < 2; ++j) {                         \
      u32 pw[4];                                                            \
      _Pragma("unroll") for (int i = 0; i < 2; ++i) {                       \
        float p0 = __builtin_amdgcn_exp2f(S[i][j][0]);                      \
        float p1 = __builtin_amdgcn_exp2f(S[i][j][1]);                      \
        float p2 = __builtin_amdgcn_exp2f(S[i][j][2]);                      \
        float p3 = __builtin_amdgcn_exp2f(S[i][j][3]);                      \
        u32 a0 = __float_as_uint(p0) + 0x8000u;                             \
        u32 a1 = __float_as_uint(p1) + 0x8000u;                             \
        u32 a2 = __float_as_uint(p2) + 0x8000u;                             \
        u32 a3 = __float_as_uint(p3) + 0x8000u;                             \
        pw[i * 2] = __builtin_amdgcn_perm(a1, a0, 0x07060302u);             \
        pw[i * 2 + 1] = __builtin_amdgcn_perm(a3, a2, 0x07060302u);         \
      }                                                                     \
      u32x4 va = {pw[0], pw[1], pw[2], pw[3]};                              \
      frag8 pf = __builtin_bit_cast(frag8, va);                             \
      __builtin_amdgcn_s_setprio(1);                                        \
      _Pragma("unroll") for (int i = 0; i < 4; ++i)                         \
          o[i][j] = MFMA(vf[i], pf, o[i][j]);                               \
      lacc[j] = MFMA(ones, pf, lacc[j]);                                    \
      __builtin_amdgcn_s_setprio(0);                                        \
    }                                                                       \
  }

__global__ __launch_bounds__(512, 4) void attn_flash_kernel(
    const u16* __restrict__ Qt, const u16* __restrict__ Kt,
    const u16* __restrict__ Vn, float* __restrict__ out) {
  __shared__ __align__(16) unsigned char smem[49152];
  u16* ldsbase = (u16*)smem;

  // XCD swizzle: blk&7 = XCD; 4 heads per XCD (K+V L2-resident per XCD)
  const int blk = blockIdx.x;
  const int ii = blk >> 3;
  const int b = ((blk & 7) << 2) + (ii >> 4);  // head 0..31
  const int qt = ii & 15;                      // q-tile (128 t each)

  const int tid = threadIdx.x;  // 0..511
  const int w = tid >> 6;
  const int tg = w & 3;   // t-group: t in [32*tg, 32*tg+32) of the q-tile
  const int sh = w >> 2;  // s-half: s in [1024*sh, 1024*sh+1024)
  const int lane = tid & 63;
  const int s16 = lane & 15, q = lane >> 4;
  const int x = s16 & 7;
  const int x2 = (s16 >> 1) & 3;

  const u16* Qg = Qt + ((size_t)b * 2048 + qt * 128) * 64;
  const u16* Kg = Kt + (size_t)b * 2048 * 64;
  const u16* Vg = Vn + (size_t)b * 64 * 2048;

  // staging source pointers (pre-swizzled; 512 threads = 2 x 256-lane groups)
  const int inner = tid & 255;
  const int gsel = tid >> 8;  // selects s-half within a staging call
  const int srow = inner >> 3;
  const int sgl = (inner & 7) ^ (srow & 7);
  const u16* kS = Kg + gsel * 65536 + srow * 64 + sgl * 8;  // K rows, pitch 64
  const u16* vS = Vg + gsel * 1024 + (inner >> 2) * 2048 +
                  ((((inner & 3) ^ ((inner >> 3) & 3))) * 8);  // V pitch 2048

  // fragment read offsets within a buffer (XOR-swizzled)
  const int kAo = sh * 2048 + s16 * 64 + ((q ^ x) * 8);
  const int kBo = sh * 2048 + s16 * 64 + (((q + 4) ^ x) * 8);
  const int vAo = 4096 + sh * 2048 + s16 * 32 + ((q ^ x2) * 8);

  // loop-invariant Q fragments, DIRECT from global (coalesced 16B/lane):
  // aQ0[j] = Q rows tg*32+16j+s16, cols q*8..; aQ1[j] cols (q+4)*8..
  frag8 aQ0[2], aQ1[2];
#pragma unroll
  for (int j = 0; j < 2; ++j) {
    const u16* qr = Qg + (size_t)(tg * 32 + j * 16 + s16) * 64;
    aQ0[j] = *(const frag8*)(qr + q * 8);
    aQ1[j] = *(const frag8*)(qr + (q + 4) * 8);
  }

  // prologue staging: tiles 0,1 -> buf0,buf1 (4 loads/thread in flight)
  STG_STEP(0, 0)
  STG_STEP(1, 8192)

  // ones A-fragment (bf16 1.0) for the row-sum MFMA
  frag8 ones;
#pragma unroll
  for (int z = 0; z < 8; ++z) ones[z] = (short)0x3F80;

  f32x4 o[4][2];
#pragma unroll
  for (int i = 0; i < 4; ++i)
#pragma unroll
    for (int j = 0; j < 2; ++j) o[i][j] = (f32x4){0.f, 0.f, 0.f, 0.f};
  f32x4 lacc[2];
#pragma unroll
  for (int j = 0; j < 2; ++j) lacc[j] = (f32x4){0.f, 0.f, 0.f, 0.f};

  // step 0: drain everything once (Q regs + tile 0; tile 1 re-waited cheaply)
  WAITB(0) BODY(0, STG_STEP(2, 16384))
  // steps 1..27: uniform vmcnt(2) -- tile n done, tile n+1 in flight
  for (int m = 0; m < 9; ++m) {
    WAITB(2) BODY(8192, STG_STEP(3 * m + 3, 0))
    WAITB(2) BODY(16384, STG_STEP(3 * m + 4, 8192))
    WAITB(2) BODY(0, STG_STEP(3 * m + 5, 16384))
  }
  // steps 28..31 (tail: last staging at step 29)
  WAITB(2) BODY(8192, STG_STEP(30, 0))
  WAITB(2) BODY(16384, STG_STEP(31, 8192))
  WAITB(2) BODY(0, )
  WAITB(0) BODY(8192, )

  __syncthreads();  // all K/V reads done before epilogue overwrites LDS

  // per-wave denominators from the ones-MFMA (all acc rows identical)
  float lp[2];
#pragma unroll
  for (int j = 0; j < 2; ++j) lp[j] = lacc[j][0];

  // combine s-halves through LDS (bufs dead now)
  // per lane: 8 f32x4 (o) + 2 floats (lp), stride 36 floats (144 B)
  float* fb = (float*)ldsbase;
  if (sh == 1) {
    float* ow = fb + tg * 2304 + lane * 36;
#pragma unroll
    for (int i = 0; i < 4; ++i)
#pragma unroll
      for (int j = 0; j < 2; ++j) *(f32x4*)(ow + (i * 2 + j) * 4) = o[i][j];
    ow[32] = lp[0];
    ow[33] = lp[1];
  }
  __syncthreads();
  if (sh == 0) {
    const float* ow = fb + tg * 2304 + lane * 36;
    float rl[2];
#pragma unroll
    for (int j = 0; j < 2; ++j) rl[j] = 1.0f / (lp[j] + ow[32 + j]);
    // lane stores O^T[c = i*16+q*4+r][t = qt*128 + tg*32 + 16j + s16]
    float* ob =
        out + (size_t)(b * 64 + q * 4) * 2048 + qt * 128 + tg * 32 + s16;
#pragma unroll
    for (int i = 0; i < 4; ++i)
#pragma unroll
      for (int j = 0; j < 2; ++j) {
        f32x4 oo = *(const f32x4*)(ow + (i * 2 + j) * 4);
#pragma unroll
        for (int r = 0; r < 4; ++r)
          ob[(size_t)(i * 16 + r) * 2048 + j * 16] =
              (o[i][j][r] + oo[r]) * rl[j];
      }
  }
}

extern "C" void kernel_launch(void* const* d_in, const int* in_sizes, int n_in,
                              void* d_out, int out_size, void* d_ws,
                              size_t ws_size, hipStream_t stream) {
  const float* qkv = (const float*)d_in[0];
  float* out = (float*)d_out;
  u16* Qt = (u16*)d_ws;
  u16* Kt = Qt + (size_t)32 * 2048 * 64;
  u16* Vn = Kt + (size_t)32 * 2048 * 64;

  qkv_prepass_kernel<<<3072, 256, 0, stream>>>(qkv, Qt, Kt, Vn);
  attn_flash_kernel<<<512, 512, 0, stream>>>(Qt, Kt, Vn, out);
}